// Round 1
// baseline (74.952 us; speedup 1.0000x reference)
//
#include <hip/hip_runtime.h>

// Projector: out[n][j][k] = scale * sum_t trilinear(vol, p(t)+63.5)
//   p(t) = dc + j_c[j]*u + k_c[k]*v + t_c[t]*ray,  j_c/k_c = idx-63.5
// Constants (X=Y=Z=128): n_depth=222, max_extent=96*sqrt(3), dt=2*me/221,
// scale=2*me/222.
//
// R4 (from R3 @ ~75us bench): kernel is VALU-issue bound, not memory bound
// (8MB volume is L2/L3-resident; the 40us fills in rocprof are harness
// workspace poison, already at HBM roofline).
//  - interior/boundary t-window split: inside (0,127)^2 no clamps/selects,
//    bilinear = 3 lerps.
//  - wave-uniform row offset -> readfirstlane -> SGPR base, loads are
//    s_base + invariant lane offset (addr math VALU->SALU).
//  - float2 k-pairing: 64 lanes cover 128 k, VMEM instrs halved, uniform
//    work amortized over 2 outputs; 8 t-slices (was 4) halve trip counts.
//  - __launch_bounds__(512,8): force VGPR<=64 so 1024 blocks x 8 waves are
//    single-round resident (32 waves/CU exact, no dispatch tail).
constexpr int ND = 222;

__global__ __launch_bounds__(512, 8) void projector_kernel(
    const float* __restrict__ vol,
    const float* __restrict__ vecs,
    float* __restrict__ out)
{
    const int rowid = blockIdx.x;          // n*128 + j
    const int n = rowid >> 7;
    const int j = rowid & 127;
    const int lane = threadIdx.x & 63;
    const int th   = threadIdx.x >> 6;     // t-slice 0..7 (wave-granular)
    const int k2   = lane << 1;            // this lane's k pair

    const float* vp = vecs + n * 12;
    const float rx = vp[0], ry = vp[1], rz = vp[2];
    const float dcx = vp[3], dcy = vp[4], dcz = vp[5];
    const float ux = vp[6], uy = vp[7], uz = vp[8];
    const float vx = vp[9], vy = vp[10], vz = vp[11];

    const float jc = (float)j - 63.5f;

    const float t0c = -166.2768775266122f;   // -max_extent
    const float dtc = 1.5047681223222824f;   // 2*me/221
    const float scale = 1.4979898876271372f; // 2*me/222

    __shared__ float2 part[8][64];

    const bool degen = (rz == 0.0f) & (uz == 0.0f) & (dcz == 0.0f) &
                       (vx == 0.0f) & (vy == 0.0f) & (vz == 1.0f);

    float acc0 = 0.0f, acc1 = 0.0f;

    if (degen) {
        // Row-uniform 2D problem in x-y; z slice == k exactly (fz==0).
        const float bx = dcx + jc * ux + 63.5f;
        const float by = dcy + jc * uy + 63.5f;

        // Full valid window [tb,te] (taps may straddle the border, clamped
        // path) and interior window [ib,ie] (all 4 taps strictly in-bounds,
        // clamp-free path). 1e-3 interior margin >> fp error (~3e-5).
        float tlo = -1e30f, thi = 1e30f;
        float ilo = -1e30f, ihi = 1e30f;
        const float bsv[2] = {bx, by};
        const float rsv[2] = {rx, ry};
        #pragma unroll
        for (int a = 0; a < 2; ++a) {
            const float b = bsv[a], r = rsv[a];
            if (fabsf(r) > 1e-8f) {
                const float inv = 1.0f / r;
                float t1 = (-1.01f - b) * inv;
                float t2 = (128.01f - b) * inv;
                tlo = fmaxf(tlo, fminf(t1, t2));
                thi = fminf(thi, fmaxf(t1, t2));
                t1 = (0.001f - b) * inv;
                t2 = (126.999f - b) * inv;
                ilo = fmaxf(ilo, fminf(t1, t2));
                ihi = fminf(ihi, fmaxf(t1, t2));
            } else {
                if (b < -1.01f || b > 128.01f)   { tlo = 1e30f; thi = -1e30f; }
                if (b < 0.001f || b > 126.999f)  { ilo = 1e30f; ihi = -1e30f; }
            }
        }
        // float-clamp before int cast (avoid UB on +-1e30)
        const float ftb = ceilf((tlo - t0c) / dtc);
        const float fte = floorf((thi - t0c) / dtc);
        int tb = (int)fmaxf(fminf(ftb, 300.0f), 0.0f);
        int te = (int)fmaxf(fminf(fte, (float)(ND - 1)), -1.0f);
        const float fib = ceilf((ilo - t0c) / dtc);
        const float fie = floorf((ihi - t0c) / dtc);
        int ib = (int)fmaxf(fminf(fib, 300.0f), 0.0f);
        int ie = (int)fmaxf(fminf(fie, (float)(ND - 1)), -1.0f);
        ib = max(ib, tb); ie = min(ie, te);
        if (ie < ib) { ib = te + 1; ie = te; }   // empty interior -> all clamped

        // slice the (block-uniform) window among the 8 waves
        const int len = max(te - tb + 1, 0);
        const int q = (len + 7) >> 3;
        const int mtb = tb + th * q;
        const int mte = min(mtb + q - 1, te);

        // clamped step (border taps; few iterations)
        auto clampStep = [&](int t) {
            const float tcf = fmaf(dtc, (float)t, t0c);
            const float ix = fmaf(tcf, rx, bx);
            const float iy = fmaf(tcf, ry, by);
            const float x0f = floorf(ix), y0f = floorf(iy);
            const float fx = ix - x0f, fy = iy - y0f;
            const int x0 = (int)x0f, y0 = (int)y0f;
            const float wx0 = ((unsigned)x0 < 128u) ? (1.0f - fx) : 0.0f;
            const float wx1 = ((unsigned)(x0 + 1) < 128u) ? fx : 0.0f;
            const float wy0 = ((unsigned)y0 < 128u) ? (1.0f - fy) : 0.0f;
            const float wy1 = ((unsigned)(y0 + 1) < 128u) ? fy : 0.0f;
            const int xa = min(max(x0, 0), 127) << 14;
            const int xb = min(max(x0 + 1, 0), 127) << 14;
            const int ya = min(max(y0, 0), 127) << 7;
            const int yb = min(max(y0 + 1, 0), 127) << 7;
            const int r00 = __builtin_amdgcn_readfirstlane(xa + ya);
            const int r01 = __builtin_amdgcn_readfirstlane(xa + yb);
            const int r10 = __builtin_amdgcn_readfirstlane(xb + ya);
            const int r11 = __builtin_amdgcn_readfirstlane(xb + yb);
            const float2 v00 = *(const float2*)(vol + r00 + k2);
            const float2 v01 = *(const float2*)(vol + r01 + k2);
            const float2 v10 = *(const float2*)(vol + r10 + k2);
            const float2 v11 = *(const float2*)(vol + r11 + k2);
            const float w00 = wx0 * wy0, w01 = wx0 * wy1;
            const float w10 = wx1 * wy0, w11 = wx1 * wy1;
            acc0 = fmaf(w00, v00.x, acc0); acc0 = fmaf(w01, v01.x, acc0);
            acc0 = fmaf(w10, v10.x, acc0); acc0 = fmaf(w11, v11.x, acc0);
            acc1 = fmaf(w00, v00.y, acc1); acc1 = fmaf(w01, v01.y, acc1);
            acc1 = fmaf(w10, v10.y, acc1); acc1 = fmaf(w11, v11.y, acc1);
        };

        // 1) low border
        const int e1 = min(mte, ib - 1);
        for (int t = mtb; t <= e1; ++t) clampStep(t);

        // 2) interior: clamp-free, scalar base, lerp-form bilinear
        const int b2 = max(mtb, ib);
        const int e2 = min(mte, ie);
        #pragma unroll 2
        for (int t = b2; t <= e2; ++t) {
            const float tcf = fmaf(dtc, (float)t, t0c);
            const float ix = fmaf(tcf, rx, bx);
            const float iy = fmaf(tcf, ry, by);
            const float x0f = floorf(ix), y0f = floorf(iy);
            const float fx = ix - x0f, fy = iy - y0f;
            const int row = ((int)x0f << 14) + ((int)y0f << 7);
            const int ru = __builtin_amdgcn_readfirstlane(row);
            const float* p = vol + ru + k2;
            const float2 v00 = *(const float2*)(p);
            const float2 v01 = *(const float2*)(p + 128);
            const float2 v10 = *(const float2*)(p + 16384);
            const float2 v11 = *(const float2*)(p + 16512);
            const float h0a = fmaf(fx, v10.x - v00.x, v00.x);
            const float h1a = fmaf(fx, v11.x - v01.x, v01.x);
            const float h0b = fmaf(fx, v10.y - v00.y, v00.y);
            const float h1b = fmaf(fx, v11.y - v01.y, v01.y);
            acc0 += fmaf(fy, h1a - h0a, h0a);
            acc1 += fmaf(fy, h1b - h0b, h0b);
        }

        // 3) high border
        const int b3 = max(mtb, ie + 1);
        for (int t = b3; t <= mte; ++t) clampStep(t);
    } else {
        // General per-lane path (unused for this input): per-k window,
        // fixed eighth of [0,ND) intersected with the analytic window.
        const int q = (ND + 7) >> 3;       // 28
        #pragma unroll
        for (int kki = 0; kki < 2; ++kki) {
            const int kk = k2 + kki;
            const float kc = (float)kk - 63.5f;
            const float bx = dcx + jc * ux + kc * vx + 63.5f;
            const float by = dcy + jc * uy + kc * vy + 63.5f;
            const float bz = dcz + jc * uz + kc * vz + 63.5f;

            float tlo = -1e30f, thi = 1e30f;
            const float bsv[3] = {bx, by, bz};
            const float rsv[3] = {rx, ry, rz};
            #pragma unroll
            for (int a = 0; a < 3; ++a) {
                const float b = bsv[a], r = rsv[a];
                if (fabsf(r) > 1e-8f) {
                    const float inv = 1.0f / r;
                    const float t1 = (-1.01f - b) * inv;
                    const float t2 = (128.01f - b) * inv;
                    tlo = fmaxf(tlo, fminf(t1, t2));
                    thi = fminf(thi, fmaxf(t1, t2));
                } else if (b < -1.01f || b > 128.01f) {
                    tlo = 1e30f; thi = -1e30f;
                }
            }
            const float ftb = ceilf((tlo - t0c) / dtc);
            const float fte = floorf((thi - t0c) / dtc);
            int tb = (int)fmaxf(fminf(ftb, 300.0f), 0.0f);
            int te = (int)fmaxf(fminf(fte, (float)(ND - 1)), -1.0f);
            tb = max(tb, th * q);
            te = min(te, min(th * q + q - 1, ND - 1));

            float facc = 0.0f;
            for (int t = tb; t <= te; ++t) {
                const float tcf = fmaf(dtc, (float)t, t0c);
                const float ix = fmaf(tcf, rx, bx);
                const float iy = fmaf(tcf, ry, by);
                const float iz = fmaf(tcf, rz, bz);
                const float x0f = floorf(ix), y0f = floorf(iy), z0f = floorf(iz);
                const float fx = ix - x0f, fy = iy - y0f, fz = iz - z0f;
                const int x0 = (int)x0f, y0 = (int)y0f, z0 = (int)z0f;
                const float wx0 = ((unsigned)x0 < 128u) ? (1.0f - fx) : 0.0f;
                const float wx1 = ((unsigned)(x0 + 1) < 128u) ? fx : 0.0f;
                const float wy0 = ((unsigned)y0 < 128u) ? (1.0f - fy) : 0.0f;
                const float wy1 = ((unsigned)(y0 + 1) < 128u) ? fy : 0.0f;
                const float wz0 = ((unsigned)z0 < 128u) ? (1.0f - fz) : 0.0f;
                const float wz1 = ((unsigned)(z0 + 1) < 128u) ? fz : 0.0f;
                const int xa = min(max(x0, 0), 127) << 14;
                const int xb = min(max(x0 + 1, 0), 127) << 14;
                const int ya = min(max(y0, 0), 127) << 7;
                const int yb = min(max(y0 + 1, 0), 127) << 7;
                const int za = min(max(z0, 0), 127);
                const int zb = min(max(z0 + 1, 0), 127);
                const float w00 = wx0 * wy0, w01 = wx0 * wy1;
                const float w10 = wx1 * wy0, w11 = wx1 * wy1;
                float s0 = w00 * vol[xa + ya + za];
                s0 = fmaf(w01, vol[xa + yb + za], s0);
                s0 = fmaf(w10, vol[xb + ya + za], s0);
                s0 = fmaf(w11, vol[xb + yb + za], s0);
                float s1 = w00 * vol[xa + ya + zb];
                s1 = fmaf(w01, vol[xa + yb + zb], s1);
                s1 = fmaf(w10, vol[xb + ya + zb], s1);
                s1 = fmaf(w11, vol[xb + yb + zb], s1);
                facc = fmaf(s0, wz0, facc);
                facc = fmaf(s1, wz1, facc);
            }
            if (kki == 0) acc0 = facc; else acc1 = facc;
        }
    }

    // reduce the 8 t-slices (float2 stride -> 2 lanes/bank: conflict-free)
    if (th != 0) part[th][lane] = make_float2(acc0, acc1);
    __syncthreads();
    if (th == 0) {
        #pragma unroll
        for (int s = 1; s < 8; ++s) {
            acc0 += part[s][lane].x;
            acc1 += part[s][lane].y;
        }
        float2 o;
        o.x = acc0 * scale;
        o.y = acc1 * scale;
        *(float2*)(out + rowid * 128 + k2) = o;
    }
}

extern "C" void kernel_launch(void* const* d_in, const int* in_sizes, int n_in,
                              void* d_out, int out_size, void* d_ws, size_t ws_size,
                              hipStream_t stream) {
    const float* vol  = (const float*)d_in[0];   // (128,128,128) fp32
    const float* vecs = (const float*)d_in[1];   // (8,12) fp32
    float* out = (float*)d_out;                  // (8,128,128) fp32

    dim3 block(512);
    dim3 grid(8 * 128);                          // one block per (n,j) row
    projector_kernel<<<grid, block, 0, stream>>>(vol, vecs, out);
}

// Round 4
// 70.942 us; speedup vs baseline: 1.0565x; 1.0565x over previous
//
#include <hip/hip_runtime.h>

// Projector: out[n][j][k] = scale * sum_t trilinear(vol, p(t)+63.5)
//   p(t) = dc + j_c[j]*u + k_c[k]*v + t_c[t]*ray,  j_c/k_c = idx-63.5
// Constants (X=Y=Z=128): n_depth=222, max_extent=96*sqrt(3), dt=2*me/221,
// scale=2*me/222.
//
// R7 == R6 resubmitted (R3 bench died on GPUAcquisitionTimeout; no data).
// R6 (from R5: swizzle alone only -4us):
//  - R5's t-split gave each of the 8 waves a CONTIGUOUS t-octant, so one
//    block touches 8 distant ray segments at once; 128 blocks/XCD => the
//    instantaneous per-XCD footprint was still the whole 8MB volume =>
//    L2 thrash survived the swizzle.
//  - STRIDED t-slicing: wave th takes t = tb+th, tb+th+8, ... All waves of
//    a block stay within +-8 steps => block footprint ~12KB; one angle's
//    128 blocks ~1.5MB < 4MB L2. Angle-per-XCD swizzle now effective:
//    each XCD streams the volume ~once from L3.
//  - R5 post-timing check failure unexplained (kernel is a pure function,
//    bijective rowid, disjoint stores); suspected infra. If it fails again,
//    drop the swizzle next round.
//  - rest unchanged: interior/border split, readfirstlane scalar row base,
//    float2 k-pairing, __launch_bounds__(512,8).
constexpr int ND = 222;

__global__ __launch_bounds__(512, 8) void projector_kernel(
    const float* __restrict__ vol,
    const float* __restrict__ vecs,
    float* __restrict__ out)
{
    // XCD swizzle: b&7 = XCD (round-robin dispatch), b>>3 = j.
    const int b = blockIdx.x;
    const int rowid = ((b & 7) << 7) | (b >> 3);   // n*128 + j
    const int n = rowid >> 7;
    const int j = rowid & 127;
    const int lane = threadIdx.x & 63;
    const int th   = threadIdx.x >> 6;     // t-phase 0..7 (wave-granular)
    const int k2   = lane << 1;            // this lane's k pair

    const float* vp = vecs + n * 12;
    const float rx = vp[0], ry = vp[1], rz = vp[2];
    const float dcx = vp[3], dcy = vp[4], dcz = vp[5];
    const float ux = vp[6], uy = vp[7], uz = vp[8];
    const float vx = vp[9], vy = vp[10], vz = vp[11];

    const float jc = (float)j - 63.5f;

    const float t0c = -166.2768775266122f;   // -max_extent
    const float dtc = 1.5047681223222824f;   // 2*me/221
    const float scale = 1.4979898876271372f; // 2*me/222

    __shared__ float2 part[8][64];

    const bool degen = (rz == 0.0f) & (uz == 0.0f) & (dcz == 0.0f) &
                       (vx == 0.0f) & (vy == 0.0f) & (vz == 1.0f);

    float acc0 = 0.0f, acc1 = 0.0f;

    if (degen) {
        // Row-uniform 2D problem in x-y; z slice == k exactly (fz==0).
        const float bx = dcx + jc * ux + 63.5f;
        const float by = dcy + jc * uy + 63.5f;

        // Full valid window [tb,te] (clamped path ok) and interior window
        // [ib,ie] (all 4 taps strictly in-bounds, clamp-free path).
        float tlo = -1e30f, thi = 1e30f;
        float ilo = -1e30f, ihi = 1e30f;
        const float bsv[2] = {bx, by};
        const float rsv[2] = {rx, ry};
        #pragma unroll
        for (int a = 0; a < 2; ++a) {
            const float bb = bsv[a], r = rsv[a];
            if (fabsf(r) > 1e-8f) {
                const float inv = 1.0f / r;
                float t1 = (-1.01f - bb) * inv;
                float t2 = (128.01f - bb) * inv;
                tlo = fmaxf(tlo, fminf(t1, t2));
                thi = fminf(thi, fmaxf(t1, t2));
                t1 = (0.001f - bb) * inv;
                t2 = (126.999f - bb) * inv;
                ilo = fmaxf(ilo, fminf(t1, t2));
                ihi = fminf(ihi, fmaxf(t1, t2));
            } else {
                if (bb < -1.01f || bb > 128.01f)   { tlo = 1e30f; thi = -1e30f; }
                if (bb < 0.001f || bb > 126.999f)  { ilo = 1e30f; ihi = -1e30f; }
            }
        }
        // float-clamp before int cast (avoid UB on +-1e30)
        const float ftb = ceilf((tlo - t0c) / dtc);
        const float fte = floorf((thi - t0c) / dtc);
        int tb = (int)fmaxf(fminf(ftb, 300.0f), 0.0f);
        int te = (int)fmaxf(fminf(fte, (float)(ND - 1)), -1.0f);
        const float fib = ceilf((ilo - t0c) / dtc);
        const float fie = floorf((ihi - t0c) / dtc);
        int ib = (int)fmaxf(fminf(fib, 300.0f), 0.0f);
        int ie = (int)fmaxf(fminf(fie, (float)(ND - 1)), -1.0f);
        ib = max(ib, tb); ie = min(ie, te);
        if (ie < ib) { ib = te + 1; ie = te; }   // empty interior -> all clamped

        // STRIDED t-slicing: this wave owns t ≡ rph (mod 8) within [tb,te].
        // Keeps all 8 waves of the block within +-8 steps of each other
        // (small, cache-coherent footprint) and balances work to +-1 step.
        const int rph = tb + th;

        // clamped step (border taps; few iterations)
        auto clampStep = [&](int t) {
            const float tcf = fmaf(dtc, (float)t, t0c);
            const float ix = fmaf(tcf, rx, bx);
            const float iy = fmaf(tcf, ry, by);
            const float x0f = floorf(ix), y0f = floorf(iy);
            const float fx = ix - x0f, fy = iy - y0f;
            const int x0 = (int)x0f, y0 = (int)y0f;
            const float wx0 = ((unsigned)x0 < 128u) ? (1.0f - fx) : 0.0f;
            const float wx1 = ((unsigned)(x0 + 1) < 128u) ? fx : 0.0f;
            const float wy0 = ((unsigned)y0 < 128u) ? (1.0f - fy) : 0.0f;
            const float wy1 = ((unsigned)(y0 + 1) < 128u) ? fy : 0.0f;
            const int xa = min(max(x0, 0), 127) << 14;
            const int xb = min(max(x0 + 1, 0), 127) << 14;
            const int ya = min(max(y0, 0), 127) << 7;
            const int yb = min(max(y0 + 1, 0), 127) << 7;
            const int r00 = __builtin_amdgcn_readfirstlane(xa + ya);
            const int r01 = __builtin_amdgcn_readfirstlane(xa + yb);
            const int r10 = __builtin_amdgcn_readfirstlane(xb + ya);
            const int r11 = __builtin_amdgcn_readfirstlane(xb + yb);
            const float2 v00 = *(const float2*)(vol + r00 + k2);
            const float2 v01 = *(const float2*)(vol + r01 + k2);
            const float2 v10 = *(const float2*)(vol + r10 + k2);
            const float2 v11 = *(const float2*)(vol + r11 + k2);
            const float w00 = wx0 * wy0, w01 = wx0 * wy1;
            const float w10 = wx1 * wy0, w11 = wx1 * wy1;
            acc0 = fmaf(w00, v00.x, acc0); acc0 = fmaf(w01, v01.x, acc0);
            acc0 = fmaf(w10, v10.x, acc0); acc0 = fmaf(w11, v11.x, acc0);
            acc1 = fmaf(w00, v00.y, acc1); acc1 = fmaf(w01, v01.y, acc1);
            acc1 = fmaf(w10, v10.y, acc1); acc1 = fmaf(w11, v11.y, acc1);
        };

        // 1) low border: [tb, ib-1], stride 8, phase rph
        {
            const int hi = min(te, ib - 1);
            int t = tb + ((rph - tb) & 7);   // (& 7) is correct mod for pow2
            for (; t <= hi; t += 8) clampStep(t);
        }

        // 2) interior: clamp-free, scalar base, lerp-form bilinear
        {
            const int lo = max(tb, ib);
            const int hi = min(te, ie);
            int t = lo + ((rph - lo) & 7);
            #pragma unroll 2
            for (; t <= hi; t += 8) {
                const float tcf = fmaf(dtc, (float)t, t0c);
                const float ix = fmaf(tcf, rx, bx);
                const float iy = fmaf(tcf, ry, by);
                const float x0f = floorf(ix), y0f = floorf(iy);
                const float fx = ix - x0f, fy = iy - y0f;
                const int row = ((int)x0f << 14) + ((int)y0f << 7);
                const int ru = __builtin_amdgcn_readfirstlane(row);
                const float* p = vol + ru + k2;
                const float2 v00 = *(const float2*)(p);
                const float2 v01 = *(const float2*)(p + 128);
                const float2 v10 = *(const float2*)(p + 16384);
                const float2 v11 = *(const float2*)(p + 16512);
                const float h0a = fmaf(fx, v10.x - v00.x, v00.x);
                const float h1a = fmaf(fx, v11.x - v01.x, v01.x);
                const float h0b = fmaf(fx, v10.y - v00.y, v00.y);
                const float h1b = fmaf(fx, v11.y - v01.y, v01.y);
                acc0 += fmaf(fy, h1a - h0a, h0a);
                acc1 += fmaf(fy, h1b - h0b, h0b);
            }
        }

        // 3) high border: [ie+1, te], stride 8, phase rph
        {
            const int lo = max(tb, ie + 1);
            int t = lo + ((rph - lo) & 7);
            for (; t <= te; t += 8) clampStep(t);
        }
    } else {
        // General per-lane path (unused for this input): per-k window,
        // strided eighth of the analytic window.
        #pragma unroll
        for (int kki = 0; kki < 2; ++kki) {
            const int kk = k2 + kki;
            const float kc = (float)kk - 63.5f;
            const float bx = dcx + jc * ux + kc * vx + 63.5f;
            const float by = dcy + jc * uy + kc * vy + 63.5f;
            const float bz = dcz + jc * uz + kc * vz + 63.5f;

            float tlo = -1e30f, thi = 1e30f;
            const float bsv[3] = {bx, by, bz};
            const float rsv[3] = {rx, ry, rz};
            #pragma unroll
            for (int a = 0; a < 3; ++a) {
                const float bb = bsv[a], r = rsv[a];
                if (fabsf(r) > 1e-8f) {
                    const float inv = 1.0f / r;
                    const float t1 = (-1.01f - bb) * inv;
                    const float t2 = (128.01f - bb) * inv;
                    tlo = fmaxf(tlo, fminf(t1, t2));
                    thi = fminf(thi, fmaxf(t1, t2));
                } else if (bb < -1.01f || bb > 128.01f) {
                    tlo = 1e30f; thi = -1e30f;
                }
            }
            const float ftb = ceilf((tlo - t0c) / dtc);
            const float fte = floorf((thi - t0c) / dtc);
            int tb = (int)fmaxf(fminf(ftb, 300.0f), 0.0f);
            int te = (int)fmaxf(fminf(fte, (float)(ND - 1)), -1.0f);

            float facc = 0.0f;
            int t = tb + th;
            for (; t <= te; t += 8) {
                const float tcf = fmaf(dtc, (float)t, t0c);
                const float ix = fmaf(tcf, rx, bx);
                const float iy = fmaf(tcf, ry, by);
                const float iz = fmaf(tcf, rz, bz);
                const float x0f = floorf(ix), y0f = floorf(iy), z0f = floorf(iz);
                const float fx = ix - x0f, fy = iy - y0f, fz = iz - z0f;
                const int x0 = (int)x0f, y0 = (int)y0f, z0 = (int)z0f;
                const float wx0 = ((unsigned)x0 < 128u) ? (1.0f - fx) : 0.0f;
                const float wx1 = ((unsigned)(x0 + 1) < 128u) ? fx : 0.0f;
                const float wy0 = ((unsigned)y0 < 128u) ? (1.0f - fy) : 0.0f;
                const float wy1 = ((unsigned)(y0 + 1) < 128u) ? fy : 0.0f;
                const float wz0 = ((unsigned)z0 < 128u) ? (1.0f - fz) : 0.0f;
                const float wz1 = ((unsigned)(z0 + 1) < 128u) ? fz : 0.0f;
                const int xa = min(max(x0, 0), 127) << 14;
                const int xb = min(max(x0 + 1, 0), 127) << 14;
                const int ya = min(max(y0, 0), 127) << 7;
                const int yb = min(max(y0 + 1, 0), 127) << 7;
                const int za = min(max(z0, 0), 127);
                const int zb = min(max(z0 + 1, 0), 127);
                const float w00 = wx0 * wy0, w01 = wx0 * wy1;
                const float w10 = wx1 * wy0, w11 = wx1 * wy1;
                float s0 = w00 * vol[xa + ya + za];
                s0 = fmaf(w01, vol[xa + yb + za], s0);
                s0 = fmaf(w10, vol[xb + ya + za], s0);
                s0 = fmaf(w11, vol[xb + yb + za], s0);
                float s1 = w00 * vol[xa + ya + zb];
                s1 = fmaf(w01, vol[xa + yb + zb], s1);
                s1 = fmaf(w10, vol[xb + ya + zb], s1);
                s1 = fmaf(w11, vol[xb + yb + zb], s1);
                facc = fmaf(s0, wz0, facc);
                facc = fmaf(s1, wz1, facc);
            }
            if (kki == 0) acc0 = facc; else acc1 = facc;
        }
    }

    // reduce the 8 t-phases (float2 stride -> 2 lanes/bank: conflict-free)
    if (th != 0) part[th][lane] = make_float2(acc0, acc1);
    __syncthreads();
    if (th == 0) {
        #pragma unroll
        for (int s = 1; s < 8; ++s) {
            acc0 += part[s][lane].x;
            acc1 += part[s][lane].y;
        }
        float2 o;
        o.x = acc0 * scale;
        o.y = acc1 * scale;
        *(float2*)(out + rowid * 128 + k2) = o;
    }
}

extern "C" void kernel_launch(void* const* d_in, const int* in_sizes, int n_in,
                              void* d_out, int out_size, void* d_ws, size_t ws_size,
                              hipStream_t stream) {
    const float* vol  = (const float*)d_in[0];   // (128,128,128) fp32
    const float* vecs = (const float*)d_in[1];   // (8,12) fp32
    float* out = (float*)d_out;                  // (8,128,128) fp32

    dim3 block(512);
    dim3 grid(8 * 128);                          // one block per (n,j) row
    projector_kernel<<<grid, block, 0, stream>>>(vol, vecs, out);
}

// Round 5
// 70.869 us; speedup vs baseline: 1.0576x; 1.0010x over previous
//
#include <hip/hip_runtime.h>

// Projector: out[n][j][k] = scale * sum_t trilinear(vol, p(t)+63.5)
//   p(t) = dc + j_c[j]*u + k_c[k]*v + t_c[t]*ray,  j_c/k_c = idx-63.5
// Constants (X=Y=Z=128): n_depth=222, max_extent=96*sqrt(3), dt=2*me/221,
// scale=2*me/222.
//
// R8 (discriminator round). History: R3=R4=74.9 (2x VALU/VMEM cut: null),
// R5=71.0 (XCD swizzle: -4us), R6=70.9 (strided-t: null). All first-
// principles floors put this kernel at <=5-10us; the stubborn ~30us beyond
// the 41us poison fill is suspected to be fixed harness graph content.
// This round applies the strongest remaining kernel-side lever (latency):
//  - 2-deep software pipeline in the interior loop: issue t+8's 4 float2
//    loads BEFORE consuming t's => compiler emits counted vmcnt, loads
//    overlap the FMA block => exposed latency halved if latency-bound.
//  - readfirstlane removed from the address chain (v->s->v round-trip was
//    pure critical-path latency; loads are VGPR-addressed regardless).
// Decision rule: dur_us ~66-68 => latency-bound, continue MLP path.
//                dur_us 69.5-71.5 => kernel <=5us, harness floor, ROOFLINE.
constexpr int ND = 222;

__global__ __launch_bounds__(512, 8) void projector_kernel(
    const float* __restrict__ vol,
    const float* __restrict__ vecs,
    float* __restrict__ out)
{
    // XCD swizzle: b&7 = XCD (round-robin dispatch), b>>3 = j.
    const int b = blockIdx.x;
    const int rowid = ((b & 7) << 7) | (b >> 3);   // n*128 + j
    const int n = rowid >> 7;
    const int j = rowid & 127;
    const int lane = threadIdx.x & 63;
    const int th   = threadIdx.x >> 6;     // t-phase 0..7 (wave-granular)
    const int k2   = lane << 1;            // this lane's k pair

    const float* vp = vecs + n * 12;
    const float rx = vp[0], ry = vp[1], rz = vp[2];
    const float dcx = vp[3], dcy = vp[4], dcz = vp[5];
    const float ux = vp[6], uy = vp[7], uz = vp[8];
    const float vx = vp[9], vy = vp[10], vz = vp[11];

    const float jc = (float)j - 63.5f;

    const float t0c = -166.2768775266122f;   // -max_extent
    const float dtc = 1.5047681223222824f;   // 2*me/221
    const float scale = 1.4979898876271372f; // 2*me/222

    __shared__ float2 part[8][64];

    const bool degen = (rz == 0.0f) & (uz == 0.0f) & (dcz == 0.0f) &
                       (vx == 0.0f) & (vy == 0.0f) & (vz == 1.0f);

    float acc0 = 0.0f, acc1 = 0.0f;

    if (degen) {
        // Row-uniform 2D problem in x-y; z slice == k exactly (fz==0).
        const float bx = dcx + jc * ux + 63.5f;
        const float by = dcy + jc * uy + 63.5f;

        // Full valid window [tb,te] (clamped path) and interior window
        // [ib,ie] (all 4 taps strictly in-bounds, clamp-free path).
        float tlo = -1e30f, thi = 1e30f;
        float ilo = -1e30f, ihi = 1e30f;
        const float bsv[2] = {bx, by};
        const float rsv[2] = {rx, ry};
        #pragma unroll
        for (int a = 0; a < 2; ++a) {
            const float bb = bsv[a], r = rsv[a];
            if (fabsf(r) > 1e-8f) {
                const float inv = 1.0f / r;
                float t1 = (-1.01f - bb) * inv;
                float t2 = (128.01f - bb) * inv;
                tlo = fmaxf(tlo, fminf(t1, t2));
                thi = fminf(thi, fmaxf(t1, t2));
                t1 = (0.001f - bb) * inv;
                t2 = (126.999f - bb) * inv;
                ilo = fmaxf(ilo, fminf(t1, t2));
                ihi = fminf(ihi, fmaxf(t1, t2));
            } else {
                if (bb < -1.01f || bb > 128.01f)   { tlo = 1e30f; thi = -1e30f; }
                if (bb < 0.001f || bb > 126.999f)  { ilo = 1e30f; ihi = -1e30f; }
            }
        }
        // float-clamp before int cast (avoid UB on +-1e30)
        const float ftb = ceilf((tlo - t0c) / dtc);
        const float fte = floorf((thi - t0c) / dtc);
        int tb = (int)fmaxf(fminf(ftb, 300.0f), 0.0f);
        int te = (int)fmaxf(fminf(fte, (float)(ND - 1)), -1.0f);
        const float fib = ceilf((ilo - t0c) / dtc);
        const float fie = floorf((ihi - t0c) / dtc);
        int ib = (int)fmaxf(fminf(fib, 300.0f), 0.0f);
        int ie = (int)fmaxf(fminf(fie, (float)(ND - 1)), -1.0f);
        ib = max(ib, tb); ie = min(ie, te);
        if (ie < ib) { ib = te + 1; ie = te; }   // empty interior -> all clamped

        // STRIDED t-slicing: this wave owns t ≡ tb+th (mod 8) within [tb,te].
        const int rph = tb + th;

        // clamped step (border taps; few iterations)
        auto clampStep = [&](int t) {
            const float tcf = fmaf(dtc, (float)t, t0c);
            const float ix = fmaf(tcf, rx, bx);
            const float iy = fmaf(tcf, ry, by);
            const float x0f = floorf(ix), y0f = floorf(iy);
            const float fx = ix - x0f, fy = iy - y0f;
            const int x0 = (int)x0f, y0 = (int)y0f;
            const float wx0 = ((unsigned)x0 < 128u) ? (1.0f - fx) : 0.0f;
            const float wx1 = ((unsigned)(x0 + 1) < 128u) ? fx : 0.0f;
            const float wy0 = ((unsigned)y0 < 128u) ? (1.0f - fy) : 0.0f;
            const float wy1 = ((unsigned)(y0 + 1) < 128u) ? fy : 0.0f;
            const int xa = min(max(x0, 0), 127) << 14;
            const int xb = min(max(x0 + 1, 0), 127) << 14;
            const int ya = min(max(y0, 0), 127) << 7;
            const int yb = min(max(y0 + 1, 0), 127) << 7;
            const float2 v00 = *(const float2*)(vol + xa + ya + k2);
            const float2 v01 = *(const float2*)(vol + xa + yb + k2);
            const float2 v10 = *(const float2*)(vol + xb + ya + k2);
            const float2 v11 = *(const float2*)(vol + xb + yb + k2);
            const float w00 = wx0 * wy0, w01 = wx0 * wy1;
            const float w10 = wx1 * wy0, w11 = wx1 * wy1;
            acc0 = fmaf(w00, v00.x, acc0); acc0 = fmaf(w01, v01.x, acc0);
            acc0 = fmaf(w10, v10.x, acc0); acc0 = fmaf(w11, v11.x, acc0);
            acc1 = fmaf(w00, v00.y, acc1); acc1 = fmaf(w01, v01.y, acc1);
            acc1 = fmaf(w10, v10.y, acc1); acc1 = fmaf(w11, v11.y, acc1);
        };

        // 1) low border: [tb, ib-1], stride 8, phase rph
        {
            const int hi = min(te, ib - 1);
            int t = tb + ((rph - tb) & 7);
            for (; t <= hi; t += 8) clampStep(t);
        }

        // 2) interior: clamp-free, 2-deep software-pipelined.
        //    Loads for iteration t+8 are issued BEFORE the FMAs of
        //    iteration t, so VMEM latency hides under compute (counted
        //    vmcnt). Weights (fx,fy) recomputed per stage - off the
        //    critical path.
        {
            const int lo = max(tb, ib);
            const int hi = min(te, ie);
            int t = lo + ((rph - lo) & 7);
            const float* volk = vol + k2;

            auto issue = [&](int tt, float2& v00, float2& v01,
                             float2& v10, float2& v11,
                             float& fx, float& fy) {
                const float tcf = fmaf(dtc, (float)tt, t0c);
                const float ix = fmaf(tcf, rx, bx);
                const float iy = fmaf(tcf, ry, by);
                const float x0f = floorf(ix), y0f = floorf(iy);
                fx = ix - x0f; fy = iy - y0f;
                const int row = ((int)x0f << 14) + ((int)y0f << 7);
                const float* p = volk + row;
                v00 = *(const float2*)(p);
                v01 = *(const float2*)(p + 128);
                v10 = *(const float2*)(p + 16384);
                v11 = *(const float2*)(p + 16512);
            };
            auto consume = [&](const float2& v00, const float2& v01,
                               const float2& v10, const float2& v11,
                               float fx, float fy) {
                const float h0a = fmaf(fx, v10.x - v00.x, v00.x);
                const float h1a = fmaf(fx, v11.x - v01.x, v01.x);
                const float h0b = fmaf(fx, v10.y - v00.y, v00.y);
                const float h1b = fmaf(fx, v11.y - v01.y, v01.y);
                acc0 += fmaf(fy, h1a - h0a, h0a);
                acc1 += fmaf(fy, h1b - h0b, h0b);
            };

            if (t <= hi) {
                float2 a00, a01, a10, a11; float fxA, fyA;
                issue(t, a00, a01, a10, a11, fxA, fyA);
                for (int tn = t + 8; tn <= hi; tn += 8) {
                    float2 b00, b01, b10, b11; float fxB, fyB;
                    issue(tn, b00, b01, b10, b11, fxB, fyB);
                    consume(a00, a01, a10, a11, fxA, fyA);
                    a00 = b00; a01 = b01; a10 = b10; a11 = b11;
                    fxA = fxB; fyA = fyB;
                }
                consume(a00, a01, a10, a11, fxA, fyA);
            }
        }

        // 3) high border: [ie+1, te], stride 8, phase rph
        {
            const int lo = max(tb, ie + 1);
            int t = lo + ((rph - lo) & 7);
            for (; t <= te; t += 8) clampStep(t);
        }
    } else {
        // General per-lane path (unused for this input): per-k window,
        // strided eighth of the analytic window.
        #pragma unroll
        for (int kki = 0; kki < 2; ++kki) {
            const int kk = k2 + kki;
            const float kc = (float)kk - 63.5f;
            const float bx = dcx + jc * ux + kc * vx + 63.5f;
            const float by = dcy + jc * uy + kc * vy + 63.5f;
            const float bz = dcz + jc * uz + kc * vz + 63.5f;

            float tlo = -1e30f, thi = 1e30f;
            const float bsv[3] = {bx, by, bz};
            const float rsv[3] = {rx, ry, rz};
            #pragma unroll
            for (int a = 0; a < 3; ++a) {
                const float bb = bsv[a], r = rsv[a];
                if (fabsf(r) > 1e-8f) {
                    const float inv = 1.0f / r;
                    const float t1 = (-1.01f - bb) * inv;
                    const float t2 = (128.01f - bb) * inv;
                    tlo = fmaxf(tlo, fminf(t1, t2));
                    thi = fminf(thi, fmaxf(t1, t2));
                } else if (bb < -1.01f || bb > 128.01f) {
                    tlo = 1e30f; thi = -1e30f;
                }
            }
            const float ftb = ceilf((tlo - t0c) / dtc);
            const float fte = floorf((thi - t0c) / dtc);
            int tb = (int)fmaxf(fminf(ftb, 300.0f), 0.0f);
            int te = (int)fmaxf(fminf(fte, (float)(ND - 1)), -1.0f);

            float facc = 0.0f;
            int t = tb + th;
            for (; t <= te; t += 8) {
                const float tcf = fmaf(dtc, (float)t, t0c);
                const float ix = fmaf(tcf, rx, bx);
                const float iy = fmaf(tcf, ry, by);
                const float iz = fmaf(tcf, rz, bz);
                const float x0f = floorf(ix), y0f = floorf(iy), z0f = floorf(iz);
                const float fx = ix - x0f, fy = iy - y0f, fz = iz - z0f;
                const int x0 = (int)x0f, y0 = (int)y0f, z0 = (int)z0f;
                const float wx0 = ((unsigned)x0 < 128u) ? (1.0f - fx) : 0.0f;
                const float wx1 = ((unsigned)(x0 + 1) < 128u) ? fx : 0.0f;
                const float wy0 = ((unsigned)y0 < 128u) ? (1.0f - fy) : 0.0f;
                const float wy1 = ((unsigned)(y0 + 1) < 128u) ? fy : 0.0f;
                const float wz0 = ((unsigned)z0 < 128u) ? (1.0f - fz) : 0.0f;
                const float wz1 = ((unsigned)(z0 + 1) < 128u) ? fz : 0.0f;
                const int xa = min(max(x0, 0), 127) << 14;
                const int xb = min(max(x0 + 1, 0), 127) << 14;
                const int ya = min(max(y0, 0), 127) << 7;
                const int yb = min(max(y0 + 1, 0), 127) << 7;
                const int za = min(max(z0, 0), 127);
                const int zb = min(max(z0 + 1, 0), 127);
                const float w00 = wx0 * wy0, w01 = wx0 * wy1;
                const float w10 = wx1 * wy0, w11 = wx1 * wy1;
                float s0 = w00 * vol[xa + ya + za];
                s0 = fmaf(w01, vol[xa + yb + za], s0);
                s0 = fmaf(w10, vol[xb + ya + za], s0);
                s0 = fmaf(w11, vol[xb + yb + za], s0);
                float s1 = w00 * vol[xa + ya + zb];
                s1 = fmaf(w01, vol[xa + yb + zb], s1);
                s1 = fmaf(w10, vol[xb + ya + zb], s1);
                s1 = fmaf(w11, vol[xb + yb + zb], s1);
                facc = fmaf(s0, wz0, facc);
                facc = fmaf(s1, wz1, facc);
            }
            if (kki == 0) acc0 = facc; else acc1 = facc;
        }
    }

    // reduce the 8 t-phases (float2 stride -> 2 lanes/bank: conflict-free)
    if (th != 0) part[th][lane] = make_float2(acc0, acc1);
    __syncthreads();
    if (th == 0) {
        #pragma unroll
        for (int s = 1; s < 8; ++s) {
            acc0 += part[s][lane].x;
            acc1 += part[s][lane].y;
        }
        float2 o;
        o.x = acc0 * scale;
        o.y = acc1 * scale;
        *(float2*)(out + rowid * 128 + k2) = o;
    }
}

extern "C" void kernel_launch(void* const* d_in, const int* in_sizes, int n_in,
                              void* d_out, int out_size, void* d_ws, size_t ws_size,
                              hipStream_t stream) {
    const float* vol  = (const float*)d_in[0];   // (128,128,128) fp32
    const float* vecs = (const float*)d_in[1];   // (8,12) fp32
    float* out = (float*)d_out;                  // (8,128,128) fp32

    dim3 block(512);
    dim3 grid(8 * 128);                          // one block per (n,j) row
    projector_kernel<<<grid, block, 0, stream>>>(vol, vecs, out);
}